// Round 11
// baseline (297.226 us; speedup 1.0000x reference)
//
#include <hip/hip_runtime.h>

// Problem constants (reference: N=100000, D=32, E=1600000, EH=32, NH=16, TAU=0.1)
#define D_FEAT 32
#define EHID 32
#define NHID 16
#define INV_TAU 10.0f
#define SCAN_CHUNK 1024
#define SDS 40      // sdiff row stride in ushorts (80B)
#define TILE 8192   // edges per tile in bucket sort
#define BSH 7       // fine-bin shift (bins of 128 nodes)
#define NBIN 128
#define BMASK 127
#define CAP 3072    // max edges per v-bin (mean 2048, +23 sigma)

typedef __attribute__((ext_vector_type(8))) short short8v;  // 8 bf16 (4 VGPRs)
typedef __attribute__((ext_vector_type(4))) float f32x4;

__device__ __forceinline__ unsigned enc_f32(float f) {
    unsigned b = __float_as_uint(f);
    return (b & 0x80000000u) ? ~b : (b | 0x80000000u);
}
__device__ __forceinline__ float dec_f32(unsigned e) {
    unsigned b = (e & 0x80000000u) ? (e & 0x7fffffffu) : ~e;
    return __uint_as_float(b);
}
__device__ __forceinline__ unsigned short f2bf(float f) {
    unsigned u = __float_as_uint(f);
    u += 0x7fffu + ((u >> 16) & 1u);   // RNE (inputs finite)
    return (unsigned short)(u >> 16);
}
__device__ __forceinline__ float bflo(unsigned u) { return __uint_as_float(u << 16); }
__device__ __forceinline__ float bfhi(unsigned u) { return __uint_as_float(u & 0xFFFF0000u); }

// ---------- KX: pack x to bf16 pairs ----------
__global__ __launch_bounds__(256) void kx_pack(const float* __restrict__ x,
                                               unsigned* __restrict__ xbf, int n2) {
    int i = blockIdx.x * 256 + threadIdx.x;
    if (i >= n2) return;
    float2 f = *(const float2*)(x + 2 * (size_t)i);
    xbf[i] = (unsigned)f2bf(f.x) | ((unsigned)f2bf(f.y) << 16);
}

// ---------- K1: hsd sum / sumsq reduction ----------
__global__ __launch_bounds__(256) void k1_hsd_stats(const float* __restrict__ hsd,
                                                    double* __restrict__ stats, int N) {
    double s = 0.0, s2 = 0.0;
    for (int i = blockIdx.x * 256 + threadIdx.x; i < N; i += gridDim.x * 256) {
        double v = (double)hsd[i];
        s += v; s2 += v * v;
    }
    for (int off = 32; off > 0; off >>= 1) {
        s  += __shfl_down(s,  off, 64);
        s2 += __shfl_down(s2, off, 64);
    }
    __shared__ double ls[4], ls2[4];
    int wid = threadIdx.x >> 6, lid = threadIdx.x & 63;
    if (lid == 0) { ls[wid] = s; ls2[wid] = s2; }
    __syncthreads();
    if (threadIdx.x == 0) {
        double ts = 0.0, t2 = 0.0;
        for (int w = 0; w < 4; ++w) { ts += ls[w]; t2 += ls2[w]; }
        atomicAdd(stats, ts);
        atomicAdd(stats + 1, t2);
    }
}

// ---------- K2: hsd_norm + gate alpha_bar ----------
__global__ __launch_bounds__(256) void k2_node_prep(const float* __restrict__ hsd,
                                                    const double* __restrict__ stats,
                                                    const float* __restrict__ Wn1,
                                                    const float* __restrict__ bn1,
                                                    const float* __restrict__ Wn2,
                                                    const float* __restrict__ bn2,
                                                    float* __restrict__ hsd_norm,
                                                    float* __restrict__ alpha_bar, int N) {
    int n = blockIdx.x * 256 + threadIdx.x;
    if (n >= N) return;
    double sum = stats[0], sumsq = stats[1];
    double mean = sum / (double)N;
    double var  = (sumsq - sum * sum / (double)N) / (double)(N - 1);
    float stdv  = (float)sqrt(var);
    float hn = (hsd[n] - (float)mean) / (stdv + 1e-8f);
    hsd_norm[n] = hn;
    float acc = bn2[0];
#pragma unroll
    for (int k = 0; k < NHID; ++k)
        acc += fmaxf(fmaf(hn, Wn1[k], bn1[k]), 0.0f) * Wn2[k];
    alpha_bar[n] = 1.0f / (1.0f + __expf(-acc));
}

// ---------- S1: per-tile fine-bin histograms ----------
__global__ __launch_bounds__(256) void s1_hist(const int* __restrict__ ei,
                                               int* __restrict__ hist,
                                               int E, int NB, int T, int M) {
    __shared__ int hv[1024], hu[1024];
    int t = threadIdx.x;
    for (int b = t; b < 1024; b += 256) { hv[b] = 0; hu[b] = 0; }
    __syncthreads();
    int base = blockIdx.x * TILE;
    for (int i = t; i < TILE; i += 256) {
        int e = base + i;
        if (e < E) {
            int u = ei[e], v = ei[E + e];
            atomicAdd(&hv[v >> BSH], 1);
            atomicAdd(&hu[u >> BSH], 1);
        }
    }
    __syncthreads();
    for (int b = t; b < NB; b += 256) {
        hist[b * T + blockIdx.x] = hv[b];
        hist[M + b * T + blockIdx.x] = hu[b];
    }
}

// ---------- Scan ----------
__global__ __launch_bounds__(256) void scan_k1(const int* __restrict__ cnt,
                                               int* __restrict__ out,
                                               int* __restrict__ partials, int N) {
    __shared__ int lds[256];
    int base = blockIdx.x * SCAN_CHUNK;
    int t = threadIdx.x;
    int v[4]; int loc = 0;
#pragma unroll
    for (int k = 0; k < 4; ++k) {
        int idx = base + t * 4 + k;
        v[k] = (idx < N) ? cnt[idx] : 0;
        loc += v[k];
    }
    lds[t] = loc; __syncthreads();
    for (int off = 1; off < 256; off <<= 1) {
        int a = (t >= off) ? lds[t - off] : 0;
        __syncthreads();
        lds[t] += a;
        __syncthreads();
    }
    int run = (t > 0) ? lds[t - 1] : 0;
    if (t == 255) partials[blockIdx.x] = lds[255];
#pragma unroll
    for (int k = 0; k < 4; ++k) {
        run += v[k];
        int idx = base + t * 4 + k;
        if (idx < N) out[idx + 1] = run;
    }
    if (blockIdx.x == 0 && t == 0) out[0] = 0;
}

__global__ __launch_bounds__(256) void scan_k2(int* __restrict__ partials, int B) {
    __shared__ int lds[256];
    int t = threadIdx.x;
    int v[4]; int loc = 0;
#pragma unroll
    for (int k = 0; k < 4; ++k) {
        int idx = t * 4 + k;
        v[k] = (idx < B) ? partials[idx] : 0;
        loc += v[k];
    }
    lds[t] = loc; __syncthreads();
    for (int off = 1; off < 256; off <<= 1) {
        int a = (t >= off) ? lds[t - off] : 0;
        __syncthreads();
        lds[t] += a;
        __syncthreads();
    }
    int run = (t > 0) ? lds[t - 1] : 0;
#pragma unroll
    for (int k = 0; k < 4; ++k) {
        int idx = t * 4 + k;
        if (idx < B) { partials[idx] = run; run += v[k]; }
    }
}

__global__ __launch_bounds__(256) void scan_k3(int* __restrict__ out,
                                               const int* __restrict__ partials, int N) {
    int i = blockIdx.x * 256 + threadIdx.x;
    if (i >= N) return;
    out[i + 1] += partials[i / SCAN_CHUNK];
}

// ---------- S2: scatter packed u|vloc into fine v-bin order; u into u-bin order ----------
__global__ __launch_bounds__(256) void s2_scatter(const int* __restrict__ ei,
                                                  const int* __restrict__ scanAll,
                                                  int* __restrict__ pkG,
                                                  int* __restrict__ coarseU,
                                                  int E, int NB, int T, int M) {
    __shared__ int curV[1024], curU[1024];
    int t = threadIdx.x;
    for (int b = t; b < NB; b += 256) {
        curV[b] = scanAll[b * T + blockIdx.x];
        curU[b] = scanAll[M + b * T + blockIdx.x] - E;
    }
    __syncthreads();
    int base = blockIdx.x * TILE;
    for (int i = t; i < TILE; i += 256) {
        int e = base + i;
        if (e < E) {
            int u = ei[e], v = ei[E + e];
            int pv = atomicAdd(&curV[v >> BSH], 1);
            pkG[pv] = u | ((v & BMASK) << 17);
            int pu = atomicAdd(&curU[u >> BSH], 1);
            coarseU[pu] = u;
        }
    }
}

// ---------- S3b: per u-bin exact count -> inv_ssrc ----------
__global__ __launch_bounds__(256) void s3b_srccnt(const int* __restrict__ coarseU,
                                                  const int* __restrict__ scanAll,
                                                  float* __restrict__ inv_ssrc,
                                                  int N, int E, int NB, int T, int M) {
    __shared__ int cnt[NBIN];
    int t = threadIdx.x;
    int bin = blockIdx.x;
    int start = scanAll[M + bin * T] - E;
    int endv  = scanAll[M + (bin + 1) * T] - E;
    if (t < NBIN) cnt[t] = 0;
    __syncthreads();
    for (int i = start + t; i < endv; i += 256) atomicAdd(&cnt[coarseU[i] & BMASK], 1);
    __syncthreads();
    int vglob = (bin << BSH) + t;
    if (t < NBIN && vglob < N) inv_ssrc[vglob] = rsqrtf(fmaxf((float)cnt[t], 1.0f));
}

// ---------- K36: fused per-bin MFMA MLP + softmax tables + coef scatter ----------
// One block (512 thr = 8 waves) per v-bin (~2048 edges). Logits never leave LDS.
__global__ __launch_bounds__(512) void k36_bin(const unsigned* __restrict__ xbf,
                                               const float* __restrict__ hsd_norm,
                                               const float* __restrict__ We1,
                                               const float* __restrict__ be1,
                                               const float* __restrict__ We2,
                                               const float* __restrict__ be2,
                                               const int* __restrict__ pkG,
                                               const int* __restrict__ scanAll,
                                               const float* __restrict__ inv_ssrc,
                                               const float* __restrict__ alpha_bar,
                                               int* __restrict__ usrc,
                                               float* __restrict__ coefG,
                                               int* __restrict__ dst_off,
                                               float* __restrict__ selfc,
                                               int N, int E, int NB, int T) {
    __shared__ int      su[CAP];               // 12 KB  u | vloc<<17
    __shared__ float    slg[CAP];              // 12 KB  logits
    __shared__ unsigned short sdiff[256 * SDS];// 20 KB  A-operand chunk
    __shared__ unsigned short sB[4 * 64 * 8];  //  4 KB  B frags
    __shared__ int      cnt[NBIN];
    __shared__ unsigned mEnc[NBIN];
    __shared__ float    den[NBIN], cA[NBIN], cB[NBIN];
    __shared__ int      base_[NBIN], cur_[NBIN];

    int t = threadIdx.x;
    int bin = blockIdx.x;
    int start = scanAll[bin * T];
    int n = scanAll[(bin + 1) * T] - start;
    if (n > CAP) n = CAP;   // statistically never hit

    // ---- B table: f = c*2+h; lane l of frag f holds 8 bf16 of We1 column ----
    if (t < 256) {
        int f = t >> 6, l = t & 63;
        int c = f >> 1, hh = f & 1;
        int col = hh * 16 + (l & 15);
        int k0 = c * 32 + (l >> 4) * 8;
        unsigned short vals[8];
#pragma unroll
        for (int b = 0; b < 8; ++b) {
            int k = k0 + b;
            int row = (k < 32) ? (k + 2) : (k == 32 ? 0 : (k == 33 ? 1 : -1));
            float w = (row >= 0) ? We1[row * EHID + col] : 0.0f;
            vals[b] = f2bf(w);
        }
        *(uint4*)&sB[(f * 64 + l) * 8] = *(const uint4*)vals;
    }
    if (t < NBIN) { cnt[t] = 0; mEnc[t] = 0u; den[t] = 0.0f; }
    __syncthreads();

    // ---- load packed edges + histogram ----
    for (int i = t; i < n; i += 512) {
        int pk = pkG[start + i];
        su[i] = pk;
        atomicAdd(&cnt[pk >> 17], 1);
    }
    __syncthreads();

    int l = t & 63, w = t >> 6;
    short8v B00 = *(const short8v*)&sB[(0 * 64 + l) * 8];
    short8v B01 = *(const short8v*)&sB[(1 * 64 + l) * 8];
    short8v B10 = *(const short8v*)&sB[(2 * 64 + l) * 8];
    short8v B11 = *(const short8v*)&sB[(3 * 64 + l) * 8];
    float blo = be1[l & 15], bhi = be1[16 + (l & 15)];
    float w2lo = We2[l & 15], w2hi = We2[16 + (l & 15)];
    float b2 = be2[0];
    int vbase = bin << BSH;

    // ---- MLP in chunks of 256 edges ----
    for (int c0 = 0; c0 < n; c0 += 256) {
        // staging: 8 lanes per edge, bf16 rows (1 cache line each)
        int q = t & 7;
#pragma unroll
        for (int k = 0; k < 4; ++k) {
            int s = (t >> 3) + 64 * k;          // edge slot in chunk
            int i = c0 + s;
            int pk = su[(i < n) ? i : (n - 1)];
            int u = pk & 0x1FFFF;
            int v = vbase + (pk >> 17);
            uint2 au = *(const uint2*)(xbf + (size_t)u * 16 + q * 2);
            uint2 av = *(const uint2*)(xbf + (size_t)v * 16 + q * 2);
            ushort4 pkd;
            pkd.x = f2bf(fabsf(bflo(au.x) - bflo(av.x)));
            pkd.y = f2bf(fabsf(bfhi(au.x) - bfhi(av.x)));
            pkd.z = f2bf(fabsf(bflo(au.y) - bflo(av.y)));
            pkd.w = f2bf(fabsf(bfhi(au.y) - bfhi(av.y)));
            *(ushort4*)&sdiff[s * SDS + q * 4] = pkd;
            if (q == 0) {
                uint4 z;
                z.x = (unsigned)f2bf(hsd_norm[u]) | ((unsigned)f2bf(hsd_norm[v]) << 16);
                z.y = 0u; z.z = 0u; z.w = 0u;
                *(uint4*)&sdiff[s * SDS + 32] = z;
            }
        }
        __syncthreads();

        // MFMA: 8 waves x 2 groups of 16 edges
#pragma unroll
        for (int gg = 0; gg < 2; ++gg) {
            int grow = (w * 2 + gg) * 16;
            int row = grow + (l & 15);
            const short8v a0 = *(const short8v*)&sdiff[row * SDS + (l >> 4) * 8];
            short8v a1 = (short8v)(short)0;
            if (l < 16) a1 = *(const short8v*)&sdiff[row * SDS + 32];
            f32x4 d0 = {blo, blo, blo, blo};
            f32x4 d1 = {bhi, bhi, bhi, bhi};
            d0 = __builtin_amdgcn_mfma_f32_16x16x32_bf16(a0, B00, d0, 0, 0, 0);
            d0 = __builtin_amdgcn_mfma_f32_16x16x32_bf16(a1, B10, d0, 0, 0, 0);
            d1 = __builtin_amdgcn_mfma_f32_16x16x32_bf16(a0, B01, d1, 0, 0, 0);
            d1 = __builtin_amdgcn_mfma_f32_16x16x32_bf16(a1, B11, d1, 0, 0, 0);
#pragma unroll
            for (int r = 0; r < 4; ++r) {
                float vsum = fmaxf(d0[r], 0.0f) * w2lo + fmaxf(d1[r], 0.0f) * w2hi;
                vsum += __shfl_xor(vsum, 1, 64);
                vsum += __shfl_xor(vsum, 2, 64);
                vsum += __shfl_xor(vsum, 4, 64);
                vsum += __shfl_xor(vsum, 8, 64);
                int eo = c0 + grow + (l >> 4) * 4 + r;
                if ((l & 15) == r && eo < n) slg[eo] = (vsum + b2) * INV_TAU;
            }
        }
        __syncthreads();
    }

    // ---- segment max ----
    for (int i = t; i < n; i += 512)
        atomicMax(&mEnc[su[i] >> 17], enc_f32(slg[i]));
    __syncthreads();
    // ---- denom ----
    for (int i = t; i < n; i += 512) {
        int vl = su[i] >> 17;
        atomicAdd(&den[vl], __expf(slg[i] - dec_f32(mEnc[vl])));
    }
    __syncthreads();
    // ---- inclusive scan of cnt ----
    for (int off = 1; off < NBIN; off <<= 1) {
        int a = 0;
        if (t < NBIN && t >= off) a = cnt[t - off];
        __syncthreads();
        if (t < NBIN) cnt[t] += a;
        __syncthreads();
    }
    if (t < NBIN) {
        int b0 = (t > 0) ? cnt[t - 1] : 0;
        base_[t] = b0; cur_[t] = b0;
        int vg = vbase + t;
        if (vg < N) {
            float ab = alpha_bar[vg];
            float d = den[t];
            float inv_den = 1.0f / (d + 1e-16f);
            int deg = cnt[t] - b0;
            cA[t] = -ab * inv_den;
            cB[t] = (1.0f - ab) * rsqrtf(fmaxf((float)deg, 1.0f));
            dst_off[vg] = start + b0;
            selfc[vg] = ab * (d * inv_den);
        }
    }
    if (bin == 0 && t == 0) dst_off[N] = E;
    __syncthreads();
    // ---- scatter sorted u + final per-edge coefficient ----
    for (int i = t; i < n; i += 512) {
        int pk = su[i];
        int vl = pk >> 17;
        int u = pk & 0x1FFFF;
        int p = start + atomicAdd(&cur_[vl], 1);
        float coef = fmaf(cA[vl], __expf(slg[i] - dec_f32(mEnc[vl])), cB[vl] * inv_ssrc[u]);
        usrc[p] = u;
        coefG[p] = coef;
    }
}

// ---------- K7: pure gather on bf16 x: 16 lanes per node, 4-deep unroll ----------
__global__ __launch_bounds__(256) void k7_gather(const unsigned* __restrict__ xbf,
                                                 const int* __restrict__ dst_off,
                                                 const int* __restrict__ usrc,
                                                 const float* __restrict__ coefG,
                                                 const float* __restrict__ selfc,
                                                 float* __restrict__ out, int N) {
    int v = blockIdx.x * 16 + (threadIdx.x >> 4);
    if (v >= N) return;
    int l = threadIdx.x & 15;

    int beg = dst_off[v], end = dst_off[v + 1];

    float a0 = 0.0f, a1 = 0.0f;
    int j = beg;
    for (; j + 3 < end; j += 4) {
        int u0 = usrc[j], u1 = usrc[j + 1], u2 = usrc[j + 2], u3 = usrc[j + 3];
        float c0 = coefG[j], c1 = coefG[j + 1], c2 = coefG[j + 2], c3 = coefG[j + 3];
        unsigned q0 = xbf[(size_t)u0 * 16 + l];
        unsigned q1 = xbf[(size_t)u1 * 16 + l];
        unsigned q2 = xbf[(size_t)u2 * 16 + l];
        unsigned q3 = xbf[(size_t)u3 * 16 + l];
        a0 = fmaf(c0, bflo(q0), a0); a1 = fmaf(c0, bfhi(q0), a1);
        a0 = fmaf(c1, bflo(q1), a0); a1 = fmaf(c1, bfhi(q1), a1);
        a0 = fmaf(c2, bflo(q2), a0); a1 = fmaf(c2, bfhi(q2), a1);
        a0 = fmaf(c3, bflo(q3), a0); a1 = fmaf(c3, bfhi(q3), a1);
    }
    for (; j < end; ++j) {
        unsigned q0 = xbf[(size_t)usrc[j] * 16 + l];
        float c0 = coefG[j];
        a0 = fmaf(c0, bflo(q0), a0); a1 = fmaf(c0, bfhi(q0), a1);
    }
    float sc = selfc[v];
    unsigned qv = xbf[(size_t)v * 16 + l];
    a0 = fmaf(sc, bflo(qv), a0);
    a1 = fmaf(sc, bfhi(qv), a1);
    float2 r; r.x = a0; r.y = a1;
    *(float2*)(out + (size_t)v * D_FEAT + 2 * l) = r;
}

extern "C" void kernel_launch(void* const* d_in, const int* in_sizes, int n_in,
                              void* d_out, int out_size, void* d_ws, size_t ws_size,
                              hipStream_t stream) {
    const float* x    = (const float*)d_in[0];
    const float* hsd  = (const float*)d_in[1];
    const float* We1  = (const float*)d_in[2];
    const float* be1  = (const float*)d_in[3];
    const float* We2  = (const float*)d_in[4];
    const float* be2  = (const float*)d_in[5];
    const float* Wn1  = (const float*)d_in[6];
    const float* bn1  = (const float*)d_in[7];
    const float* Wn2  = (const float*)d_in[8];
    const float* bn2  = (const float*)d_in[9];
    const int*   ei   = (const int*)d_in[10];
    float* out = (float*)d_out;

    const int N = in_sizes[1];
    const int E = in_sizes[10] / 2;
    const int NB = (N + NBIN - 1) >> BSH;
    const int T  = (E + TILE - 1) / TILE;
    const int M  = NB * T;
    const int M2 = 2 * M;

    char* ws = (char*)d_ws;
    size_t o = 0;
    auto alloc = [&](size_t bytes) { size_t r = o; o += (bytes + 255) & ~(size_t)255; return r; };
    double* stats     = (double*)(ws + alloc(16));
    float*  inv_ssrc  = (float*)(ws + alloc((size_t)4 * N));
    float*  hsd_norm  = (float*)(ws + alloc((size_t)4 * N));
    float*  alpha_bar = (float*)(ws + alloc((size_t)4 * N));
    float*  selfc     = (float*)(ws + alloc((size_t)4 * N));
    int*    dst_off   = (int*)(ws + alloc((size_t)4 * (N + 1)));
    int*    partials  = (int*)(ws + alloc(4096));
    int*    bufH      = (int*)(ws + alloc((size_t)4 * M2));
    int*    bufS      = (int*)(ws + alloc((size_t)4 * (M2 + 1)));
    int*    pkG       = (int*)(ws + alloc((size_t)4 * E));
    int*    coarseU   = (int*)(ws + alloc((size_t)4 * E));
    int*    usrc      = (int*)(ws + alloc((size_t)4 * E));
    float*  coefG     = (float*)(ws + alloc((size_t)4 * E));
    unsigned* xbf     = (unsigned*)(ws + alloc((size_t)4 * N * 16));  // bf16 x, 64B/row

    hipMemsetAsync(d_ws, 0, 256, stream);

    kx_pack<<<(N * (D_FEAT / 2) + 255) / 256, 256, 0, stream>>>(x, xbf, N * (D_FEAT / 2));
    k1_hsd_stats<<<256, 256, 0, stream>>>(hsd, stats, N);
    k2_node_prep<<<(N + 255) / 256, 256, 0, stream>>>(hsd, stats, Wn1, bn1, Wn2, bn2,
                                                      hsd_norm, alpha_bar, N);

    s1_hist<<<T, 256, 0, stream>>>(ei, bufH, E, NB, T, M);

    int Bs = (M2 + SCAN_CHUNK - 1) / SCAN_CHUNK;
    scan_k1<<<Bs, 256, 0, stream>>>(bufH, bufS, partials, M2);
    scan_k2<<<1, 256, 0, stream>>>(partials, Bs);
    scan_k3<<<(M2 + 255) / 256, 256, 0, stream>>>(bufS, partials, M2);

    s2_scatter<<<T, 256, 0, stream>>>(ei, bufS, pkG, coarseU, E, NB, T, M);
    s3b_srccnt<<<NB, 256, 0, stream>>>(coarseU, bufS, inv_ssrc, N, E, NB, T, M);
    k36_bin<<<NB, 512, 0, stream>>>(xbf, hsd_norm, We1, be1, We2, be2, pkG, bufS,
                                    inv_ssrc, alpha_bar, usrc, coefG, dst_off, selfc,
                                    N, E, NB, T);
    k7_gather<<<(N + 15) / 16, 256, 0, stream>>>(xbf, dst_off, usrc, coefG, selfc, out, N);
}

// Round 12
// 288.624 us; speedup vs baseline: 1.0298x; 1.0298x over previous
//
#include <hip/hip_runtime.h>

// Problem constants (reference: N=100000, D=32, E=1600000, EH=32, NH=16, TAU=0.1)
#define D_FEAT 32
#define EHID 32
#define NHID 16
#define INV_TAU 10.0f
#define SCAN_CHUNK 1024
#define EPB 256     // edges per block in k3d
#define SDS 40      // sdiff row stride in ushorts (80B)
#define TILE 8192   // edges per tile in bucket sort
#define BSH 7       // fine-bin shift (bins of 128 nodes)
#define NBIN 128
#define BMASK 127
#define CAP 3072    // max edges per v-bin (mean 2048)

typedef __attribute__((ext_vector_type(8))) short short8v;  // 8 bf16 (4 VGPRs)
typedef __attribute__((ext_vector_type(4))) float f32x4;

__device__ __forceinline__ unsigned enc_f32(float f) {
    unsigned b = __float_as_uint(f);
    return (b & 0x80000000u) ? ~b : (b | 0x80000000u);
}
__device__ __forceinline__ float dec_f32(unsigned e) {
    unsigned b = (e & 0x80000000u) ? (e & 0x7fffffffu) : ~e;
    return __uint_as_float(b);
}
__device__ __forceinline__ unsigned short f2bf(float f) {
    unsigned u = __float_as_uint(f);
    u += 0x7fffu + ((u >> 16) & 1u);   // RNE (inputs finite)
    return (unsigned short)(u >> 16);
}
__device__ __forceinline__ float bflo(unsigned u) { return __uint_as_float(u << 16); }
__device__ __forceinline__ float bfhi(unsigned u) { return __uint_as_float(u & 0xFFFF0000u); }

// ---------- KX: pack x to bf16 pairs ----------
__global__ __launch_bounds__(256) void kx_pack(const float* __restrict__ x,
                                               unsigned* __restrict__ xbf, int n2) {
    int i = blockIdx.x * 256 + threadIdx.x;
    if (i >= n2) return;
    float2 f = *(const float2*)(x + 2 * (size_t)i);
    xbf[i] = (unsigned)f2bf(f.x) | ((unsigned)f2bf(f.y) << 16);
}

// ---------- K1: hsd sum / sumsq reduction ----------
__global__ __launch_bounds__(256) void k1_hsd_stats(const float* __restrict__ hsd,
                                                    double* __restrict__ stats, int N) {
    double s = 0.0, s2 = 0.0;
    for (int i = blockIdx.x * 256 + threadIdx.x; i < N; i += gridDim.x * 256) {
        double v = (double)hsd[i];
        s += v; s2 += v * v;
    }
    for (int off = 32; off > 0; off >>= 1) {
        s  += __shfl_down(s,  off, 64);
        s2 += __shfl_down(s2, off, 64);
    }
    __shared__ double ls[4], ls2[4];
    int wid = threadIdx.x >> 6, lid = threadIdx.x & 63;
    if (lid == 0) { ls[wid] = s; ls2[wid] = s2; }
    __syncthreads();
    if (threadIdx.x == 0) {
        double ts = 0.0, t2 = 0.0;
        for (int w = 0; w < 4; ++w) { ts += ls[w]; t2 += ls2[w]; }
        atomicAdd(stats, ts);
        atomicAdd(stats + 1, t2);
    }
}

// ---------- K2: hsd_norm + gate alpha_bar ----------
__global__ __launch_bounds__(256) void k2_node_prep(const float* __restrict__ hsd,
                                                    const double* __restrict__ stats,
                                                    const float* __restrict__ Wn1,
                                                    const float* __restrict__ bn1,
                                                    const float* __restrict__ Wn2,
                                                    const float* __restrict__ bn2,
                                                    float* __restrict__ hsd_norm,
                                                    float* __restrict__ alpha_bar, int N) {
    int n = blockIdx.x * 256 + threadIdx.x;
    if (n >= N) return;
    double sum = stats[0], sumsq = stats[1];
    double mean = sum / (double)N;
    double var  = (sumsq - sum * sum / (double)N) / (double)(N - 1);
    float stdv  = (float)sqrt(var);
    float hn = (hsd[n] - (float)mean) / (stdv + 1e-8f);
    hsd_norm[n] = hn;
    float acc = bn2[0];
#pragma unroll
    for (int k = 0; k < NHID; ++k)
        acc += fmaxf(fmaf(hn, Wn1[k], bn1[k]), 0.0f) * Wn2[k];
    alpha_bar[n] = 1.0f / (1.0f + __expf(-acc));
}

// ---------- S1: per-tile fine-bin histograms ----------
__global__ __launch_bounds__(256) void s1_hist(const int* __restrict__ ei,
                                               int* __restrict__ hist,
                                               int E, int NB, int T, int M) {
    __shared__ int hv[1024], hu[1024];
    int t = threadIdx.x;
    for (int b = t; b < 1024; b += 256) { hv[b] = 0; hu[b] = 0; }
    __syncthreads();
    int base = blockIdx.x * TILE;
    for (int i = t; i < TILE; i += 256) {
        int e = base + i;
        if (e < E) {
            int u = ei[e], v = ei[E + e];
            atomicAdd(&hv[v >> BSH], 1);
            atomicAdd(&hu[u >> BSH], 1);
        }
    }
    __syncthreads();
    for (int b = t; b < NB; b += 256) {
        hist[b * T + blockIdx.x] = hv[b];
        hist[M + b * T + blockIdx.x] = hu[b];
    }
}

// ---------- Scan ----------
__global__ __launch_bounds__(256) void scan_k1(const int* __restrict__ cnt,
                                               int* __restrict__ out,
                                               int* __restrict__ partials, int N) {
    __shared__ int lds[256];
    int base = blockIdx.x * SCAN_CHUNK;
    int t = threadIdx.x;
    int v[4]; int loc = 0;
#pragma unroll
    for (int k = 0; k < 4; ++k) {
        int idx = base + t * 4 + k;
        v[k] = (idx < N) ? cnt[idx] : 0;
        loc += v[k];
    }
    lds[t] = loc; __syncthreads();
    for (int off = 1; off < 256; off <<= 1) {
        int a = (t >= off) ? lds[t - off] : 0;
        __syncthreads();
        lds[t] += a;
        __syncthreads();
    }
    int run = (t > 0) ? lds[t - 1] : 0;
    if (t == 255) partials[blockIdx.x] = lds[255];
#pragma unroll
    for (int k = 0; k < 4; ++k) {
        run += v[k];
        int idx = base + t * 4 + k;
        if (idx < N) out[idx + 1] = run;
    }
    if (blockIdx.x == 0 && t == 0) out[0] = 0;
}

__global__ __launch_bounds__(256) void scan_k2(int* __restrict__ partials, int B) {
    __shared__ int lds[256];
    int t = threadIdx.x;
    int v[4]; int loc = 0;
#pragma unroll
    for (int k = 0; k < 4; ++k) {
        int idx = t * 4 + k;
        v[k] = (idx < B) ? partials[idx] : 0;
        loc += v[k];
    }
    lds[t] = loc; __syncthreads();
    for (int off = 1; off < 256; off <<= 1) {
        int a = (t >= off) ? lds[t - off] : 0;
        __syncthreads();
        lds[t] += a;
        __syncthreads();
    }
    int run = (t > 0) ? lds[t - 1] : 0;
#pragma unroll
    for (int k = 0; k < 4; ++k) {
        int idx = t * 4 + k;
        if (idx < B) { partials[idx] = run; run += v[k]; }
    }
}

__global__ __launch_bounds__(256) void scan_k3(int* __restrict__ out,
                                               const int* __restrict__ partials, int N) {
    int i = blockIdx.x * 256 + threadIdx.x;
    if (i >= N) return;
    out[i + 1] += partials[i / SCAN_CHUNK];
}

// ---------- S2: scatter edges into fine v-bin order; u into fine u-bin order ----------
__global__ __launch_bounds__(256) void s2_scatter(const int* __restrict__ ei,
                                                  const int* __restrict__ scanAll,
                                                  int2* __restrict__ coarse,
                                                  int* __restrict__ coarseU,
                                                  int E, int NB, int T, int M) {
    __shared__ int curV[1024], curU[1024];
    int t = threadIdx.x;
    for (int b = t; b < NB; b += 256) {
        curV[b] = scanAll[b * T + blockIdx.x];
        curU[b] = scanAll[M + b * T + blockIdx.x] - E;
    }
    __syncthreads();
    int base = blockIdx.x * TILE;
    for (int i = t; i < TILE; i += 256) {
        int e = base + i;
        if (e < E) {
            int u = ei[e], v = ei[E + e];
            int pv = atomicAdd(&curV[v >> BSH], 1);
            coarse[pv] = make_int2(u, v);
            int pu = atomicAdd(&curU[u >> BSH], 1);
            coarseU[pu] = u;
        }
    }
}

// ---------- S3b: per u-bin exact count -> inv_ssrc ----------
__global__ __launch_bounds__(256) void s3b_srccnt(const int* __restrict__ coarseU,
                                                  const int* __restrict__ scanAll,
                                                  float* __restrict__ inv_ssrc,
                                                  int N, int E, int NB, int T, int M) {
    __shared__ int cnt[NBIN];
    int t = threadIdx.x;
    int bin = blockIdx.x;
    int start = scanAll[M + bin * T] - E;
    int endv  = scanAll[M + (bin + 1) * T] - E;
    if (t < NBIN) cnt[t] = 0;
    __syncthreads();
    for (int i = start + t; i < endv; i += 256) atomicAdd(&cnt[coarseU[i] & BMASK], 1);
    __syncthreads();
    int vglob = (bin << BSH) + t;
    if (t < NBIN && vglob < N) inv_ssrc[vglob] = rsqrtf(fmaxf((float)cnt[t], 1.0f));
}

// ---------- K3d: edge MLP via MFMA (16x16x32 bf16), bf16 x rows (1 line per gather) ----------
__global__ __launch_bounds__(256) void k3d_mlp(const unsigned* __restrict__ xbf,
                                               const float* __restrict__ hsd_norm,
                                               const float* __restrict__ We1,
                                               const float* __restrict__ be1,
                                               const float* __restrict__ We2,
                                               const float* __restrict__ be2,
                                               const int2* __restrict__ esorted,
                                               float* __restrict__ logit, int E) {
    __shared__ unsigned short sdiff[EPB * SDS];   // 20 KB: A operand tiles
    __shared__ unsigned short sB[4 * 64 * 8];     // 4 KB: B frags

    int t = threadIdx.x;
    // ---- build B table: f = c*2+h; lane l of frag f holds 8 bf16 ----
    {
        int f = t >> 6, l = t & 63;
        int c = f >> 1, hh = f & 1;
        int col = hh * 16 + (l & 15);
        int k0 = c * 32 + (l >> 4) * 8;
        unsigned short vals[8];
#pragma unroll
        for (int b = 0; b < 8; ++b) {
            int k = k0 + b;
            int row = (k < 32) ? (k + 2) : (k == 32 ? 0 : (k == 33 ? 1 : -1));
            float w = (row >= 0) ? We1[row * EHID + col] : 0.0f;
            vals[b] = f2bf(w);
        }
        *(uint4*)&sB[(f * 64 + l) * 8] = *(const uint4*)vals;
    }

    // ---- cooperative diff build: 8 lanes per edge, bf16 rows ----
    int base = blockIdx.x * EPB;
    int q = t & 7;
#pragma unroll
    for (int k = 0; k < 8; ++k) {
        int s = (t >> 3) + 32 * k;
        int e = base + s;
        int ec = (e < E) ? e : (E - 1);
        int2 uv = esorted[ec];
        uint2 au = *(const uint2*)(xbf + (size_t)uv.x * 16 + q * 2);
        uint2 av = *(const uint2*)(xbf + (size_t)uv.y * 16 + q * 2);
        ushort4 pk;
        pk.x = f2bf(fabsf(bflo(au.x) - bflo(av.x)));
        pk.y = f2bf(fabsf(bfhi(au.x) - bfhi(av.x)));
        pk.z = f2bf(fabsf(bflo(au.y) - bflo(av.y)));
        pk.w = f2bf(fabsf(bfhi(au.y) - bfhi(av.y)));
        *(ushort4*)&sdiff[s * SDS + 4 * q] = pk;
        if (q == 0) {   // k=32..39: hsd_u, hsd_v, zeros
            uint4 z;
            z.x = (unsigned)f2bf(hsd_norm[uv.x]) | ((unsigned)f2bf(hsd_norm[uv.y]) << 16);
            z.y = 0u; z.z = 0u; z.w = 0u;
            *(uint4*)&sdiff[s * SDS + 32] = z;
        }
    }
    __syncthreads();

    // ---- MFMA: each wave does 4 groups of 16 edges ----
    int l = t & 63, w = t >> 6;
    short8v B00 = *(const short8v*)&sB[(0 * 64 + l) * 8];
    short8v B01 = *(const short8v*)&sB[(1 * 64 + l) * 8];
    short8v B10 = *(const short8v*)&sB[(2 * 64 + l) * 8];
    short8v B11 = *(const short8v*)&sB[(3 * 64 + l) * 8];
    float blo = be1[l & 15], bhi = be1[16 + (l & 15)];
    float w2lo = We2[l & 15], w2hi = We2[16 + (l & 15)];
    float b2 = be2[0];
    int wbase = base + w * 64;

#pragma unroll
    for (int g = 0; g < 4; ++g) {
        int row = g * 16 + (l & 15) + w * 64;
        const short8v a0 = *(const short8v*)&sdiff[row * SDS + (l >> 4) * 8];
        short8v a1 = (short8v)(short)0;
        if (l < 16) a1 = *(const short8v*)&sdiff[row * SDS + 32];
        f32x4 c0 = {blo, blo, blo, blo};
        f32x4 c1 = {bhi, bhi, bhi, bhi};
        c0 = __builtin_amdgcn_mfma_f32_16x16x32_bf16(a0, B00, c0, 0, 0, 0);
        c0 = __builtin_amdgcn_mfma_f32_16x16x32_bf16(a1, B10, c0, 0, 0, 0);
        c1 = __builtin_amdgcn_mfma_f32_16x16x32_bf16(a0, B01, c1, 0, 0, 0);
        c1 = __builtin_amdgcn_mfma_f32_16x16x32_bf16(a1, B11, c1, 0, 0, 0);
#pragma unroll
        for (int r = 0; r < 4; ++r) {
            float vsum = fmaxf(c0[r], 0.0f) * w2lo + fmaxf(c1[r], 0.0f) * w2hi;
            vsum += __shfl_xor(vsum, 1, 64);
            vsum += __shfl_xor(vsum, 2, 64);
            vsum += __shfl_xor(vsum, 4, 64);
            vsum += __shfl_xor(vsum, 8, 64);
            int eo = wbase + g * 16 + (l >> 4) * 4 + r;
            if ((l & 15) == r && eo < E) logit[eo] = (vsum + b2) * INV_TAU;
        }
    }
}

// ---------- K6a: per-bin tables + sorted scatter of per-edge coefficients ----------
__global__ __launch_bounds__(512) void k6a_tab(const int2* __restrict__ coarse,
                                               const float* __restrict__ logit,
                                               const int* __restrict__ scanAll,
                                               const float* __restrict__ inv_ssrc,
                                               const float* __restrict__ alpha_bar,
                                               int* __restrict__ usrc,
                                               float* __restrict__ coefG,
                                               int* __restrict__ dst_off,
                                               float* __restrict__ selfc,
                                               int N, int E, int NB, int T) {
    __shared__ int      su[CAP];
    __shared__ float    slg[CAP];
    __shared__ int      cnt[NBIN];
    __shared__ unsigned mEnc[NBIN];
    __shared__ float    den[NBIN], cA[NBIN], cB[NBIN];
    __shared__ int      base_[NBIN], cur_[NBIN];

    int t = threadIdx.x;
    int bin = blockIdx.x;
    int start = scanAll[bin * T];
    int n = scanAll[(bin + 1) * T] - start;
    if (n > CAP) n = CAP;

    if (t < NBIN) { cnt[t] = 0; mEnc[t] = 0u; den[t] = 0.0f; }
    __syncthreads();

    for (int i = t; i < n; i += 512) {
        int2 c = coarse[start + i];
        float lgv = logit[start + i];
        int vl = c.y & BMASK;
        su[i] = c.x | (vl << 17);
        slg[i] = lgv;
        atomicAdd(&cnt[vl], 1);
        atomicMax(&mEnc[vl], enc_f32(lgv));
    }
    __syncthreads();

    for (int i = t; i < n; i += 512) {
        int vl = su[i] >> 17;
        atomicAdd(&den[vl], __expf(slg[i] - dec_f32(mEnc[vl])));
    }
    __syncthreads();

    for (int off = 1; off < NBIN; off <<= 1) {
        int a = 0;
        if (t < NBIN && t >= off) a = cnt[t - off];
        __syncthreads();
        if (t < NBIN) cnt[t] += a;
        __syncthreads();
    }
    if (t < NBIN) {
        int b0 = (t > 0) ? cnt[t - 1] : 0;
        base_[t] = b0; cur_[t] = b0;
        int vg = (bin << BSH) + t;
        if (vg < N) {
            float ab = alpha_bar[vg];
            float d = den[t];
            float inv_den = 1.0f / (d + 1e-16f);
            int deg = cnt[t] - b0;
            cA[t] = -ab * inv_den;
            cB[t] = (1.0f - ab) * rsqrtf(fmaxf((float)deg, 1.0f));
            dst_off[vg] = start + b0;
            selfc[vg] = ab * (d * inv_den);
        }
    }
    if (bin == 0 && t == 0) dst_off[N] = E;
    __syncthreads();

    for (int i = t; i < n; i += 512) {
        int up = su[i];
        int vl = up >> 17;
        int u = up & 0x1FFFF;
        int p = start + atomicAdd(&cur_[vl], 1);
        float coef = fmaf(cA[vl], __expf(slg[i] - dec_f32(mEnc[vl])), cB[vl] * inv_ssrc[u]);
        usrc[p] = u;
        coefG[p] = coef;
    }
}

// ---------- K7: pure gather on bf16 x: 16 lanes per node, 4-deep unroll ----------
__global__ __launch_bounds__(256) void k7_gather(const unsigned* __restrict__ xbf,
                                                 const int* __restrict__ dst_off,
                                                 const int* __restrict__ usrc,
                                                 const float* __restrict__ coefG,
                                                 const float* __restrict__ selfc,
                                                 float* __restrict__ out, int N) {
    int v = blockIdx.x * 16 + (threadIdx.x >> 4);
    if (v >= N) return;
    int l = threadIdx.x & 15;

    int beg = dst_off[v], end = dst_off[v + 1];

    float a0 = 0.0f, a1 = 0.0f;
    int j = beg;
    for (; j + 3 < end; j += 4) {
        int u0 = usrc[j], u1 = usrc[j + 1], u2 = usrc[j + 2], u3 = usrc[j + 3];
        float c0 = coefG[j], c1 = coefG[j + 1], c2 = coefG[j + 2], c3 = coefG[j + 3];
        unsigned q0 = xbf[(size_t)u0 * 16 + l];
        unsigned q1 = xbf[(size_t)u1 * 16 + l];
        unsigned q2 = xbf[(size_t)u2 * 16 + l];
        unsigned q3 = xbf[(size_t)u3 * 16 + l];
        a0 = fmaf(c0, bflo(q0), a0); a1 = fmaf(c0, bfhi(q0), a1);
        a0 = fmaf(c1, bflo(q1), a0); a1 = fmaf(c1, bfhi(q1), a1);
        a0 = fmaf(c2, bflo(q2), a0); a1 = fmaf(c2, bfhi(q2), a1);
        a0 = fmaf(c3, bflo(q3), a0); a1 = fmaf(c3, bfhi(q3), a1);
    }
    for (; j < end; ++j) {
        unsigned q0 = xbf[(size_t)usrc[j] * 16 + l];
        float c0 = coefG[j];
        a0 = fmaf(c0, bflo(q0), a0); a1 = fmaf(c0, bfhi(q0), a1);
    }
    float sc = selfc[v];
    unsigned qv = xbf[(size_t)v * 16 + l];
    a0 = fmaf(sc, bflo(qv), a0);
    a1 = fmaf(sc, bfhi(qv), a1);
    float2 r; r.x = a0; r.y = a1;
    *(float2*)(out + (size_t)v * D_FEAT + 2 * l) = r;
}

extern "C" void kernel_launch(void* const* d_in, const int* in_sizes, int n_in,
                              void* d_out, int out_size, void* d_ws, size_t ws_size,
                              hipStream_t stream) {
    const float* x    = (const float*)d_in[0];
    const float* hsd  = (const float*)d_in[1];
    const float* We1  = (const float*)d_in[2];
    const float* be1  = (const float*)d_in[3];
    const float* We2  = (const float*)d_in[4];
    const float* be2  = (const float*)d_in[5];
    const float* Wn1  = (const float*)d_in[6];
    const float* bn1  = (const float*)d_in[7];
    const float* Wn2  = (const float*)d_in[8];
    const float* bn2  = (const float*)d_in[9];
    const int*   ei   = (const int*)d_in[10];
    float* out = (float*)d_out;

    const int N = in_sizes[1];
    const int E = in_sizes[10] / 2;
    const int NB = (N + NBIN - 1) >> BSH;
    const int T  = (E + TILE - 1) / TILE;
    const int M  = NB * T;
    const int M2 = 2 * M;

    char* ws = (char*)d_ws;
    size_t o = 0;
    auto alloc = [&](size_t bytes) { size_t r = o; o += (bytes + 255) & ~(size_t)255; return r; };
    double* stats     = (double*)(ws + alloc(16));
    float*  inv_ssrc  = (float*)(ws + alloc((size_t)4 * N));
    float*  hsd_norm  = (float*)(ws + alloc((size_t)4 * N));
    float*  alpha_bar = (float*)(ws + alloc((size_t)4 * N));
    float*  selfc     = (float*)(ws + alloc((size_t)4 * N));
    int*    dst_off   = (int*)(ws + alloc((size_t)4 * (N + 1)));
    int*    partials  = (int*)(ws + alloc(4096));
    int*    bufH      = (int*)(ws + alloc((size_t)4 * M2));
    int*    bufS      = (int*)(ws + alloc((size_t)4 * (M2 + 1)));
    int2*   coarse    = (int2*)(ws + alloc((size_t)8 * E));
    int*    coarseU   = (int*)(ws + alloc((size_t)4 * E));   // dead after s3b -> xbf
    float*  logit     = (float*)(ws + alloc((size_t)4 * E));
    int*    usrc      = (int*)(ws + alloc((size_t)4 * E));
    float*  coefG     = (float*)(ws + alloc((size_t)4 * E));
    unsigned* xbf     = (unsigned*)coarseU;   // bf16 x rows, written after s3b

    hipMemsetAsync(d_ws, 0, 256, stream);

    k1_hsd_stats<<<256, 256, 0, stream>>>(hsd, stats, N);
    k2_node_prep<<<(N + 255) / 256, 256, 0, stream>>>(hsd, stats, Wn1, bn1, Wn2, bn2,
                                                      hsd_norm, alpha_bar, N);

    s1_hist<<<T, 256, 0, stream>>>(ei, bufH, E, NB, T, M);

    int Bs = (M2 + SCAN_CHUNK - 1) / SCAN_CHUNK;
    scan_k1<<<Bs, 256, 0, stream>>>(bufH, bufS, partials, M2);
    scan_k2<<<1, 256, 0, stream>>>(partials, Bs);
    scan_k3<<<(M2 + 255) / 256, 256, 0, stream>>>(bufS, partials, M2);

    s2_scatter<<<T, 256, 0, stream>>>(ei, bufS, coarse, coarseU, E, NB, T, M);
    s3b_srccnt<<<NB, 256, 0, stream>>>(coarseU, bufS, inv_ssrc, N, E, NB, T, M);
    kx_pack<<<(N * (D_FEAT / 2) + 255) / 256, 256, 0, stream>>>(x, xbf, N * (D_FEAT / 2));
    k3d_mlp<<<(E + EPB - 1) / EPB, 256, 0, stream>>>(xbf, hsd_norm, We1, be1, We2, be2,
                                                     coarse, logit, E);
    k6a_tab<<<NB, 512, 0, stream>>>(coarse, logit, bufS, inv_ssrc, alpha_bar,
                                    usrc, coefG, dst_off, selfc, N, E, NB, T);
    k7_gather<<<(N + 15) / 16, 256, 0, stream>>>(xbf, dst_off, usrc, coefG, selfc, out, N);
}

// Round 13
// 269.777 us; speedup vs baseline: 1.1017x; 1.0699x over previous
//
#include <hip/hip_runtime.h>

// Problem constants (reference: N=100000, D=32, E=1600000, EH=32, NH=16, TAU=0.1)
#define D_FEAT 32
#define EHID 32
#define NHID 16
#define INV_TAU 10.0f
#define SCAN_CHUNK 1024
#define EPB 256     // edges per block in k3e
#define TPAD 272    // chunk stride (bytes) inside a 16-edge tile (256 + 16 pad)
#define TILE_B (4 * TPAD)   // 1088 B per 16-edge tile
#define TILE 8192   // edges per tile in bucket sort
#define BSH 7       // fine-bin shift (bins of 128 nodes)
#define NBIN 128
#define BMASK 127
#define CAP 3072    // max edges per v-bin (mean 2048)

typedef __attribute__((ext_vector_type(8))) short short8v;  // 8 bf16 (4 VGPRs)
typedef __attribute__((ext_vector_type(4))) float f32x4;

__device__ __forceinline__ unsigned enc_f32(float f) {
    unsigned b = __float_as_uint(f);
    return (b & 0x80000000u) ? ~b : (b | 0x80000000u);
}
__device__ __forceinline__ float dec_f32(unsigned e) {
    unsigned b = (e & 0x80000000u) ? (e & 0x7fffffffu) : ~e;
    return __uint_as_float(b);
}
__device__ __forceinline__ unsigned short f2bf(float f) {
    unsigned u = __float_as_uint(f);
    u += 0x7fffu + ((u >> 16) & 1u);   // RNE (inputs finite)
    return (unsigned short)(u >> 16);
}
__device__ __forceinline__ float bflo(unsigned u) { return __uint_as_float(u << 16); }
__device__ __forceinline__ float bfhi(unsigned u) { return __uint_as_float(u & 0xFFFF0000u); }
__device__ __forceinline__ unsigned pkdiff(unsigned a, unsigned b) {
    float d0 = fabsf(bflo(a) - bflo(b));
    float d1 = fabsf(bfhi(a) - bfhi(b));
    return (unsigned)f2bf(d0) | ((unsigned)f2bf(d1) << 16);
}

// ---------- KX: pack x to bf16 pairs ----------
__global__ __launch_bounds__(256) void kx_pack(const float* __restrict__ x,
                                               unsigned* __restrict__ xbf, int n2) {
    int i = blockIdx.x * 256 + threadIdx.x;
    if (i >= n2) return;
    float2 f = *(const float2*)(x + 2 * (size_t)i);
    xbf[i] = (unsigned)f2bf(f.x) | ((unsigned)f2bf(f.y) << 16);
}

// ---------- K1: hsd sum / sumsq reduction ----------
__global__ __launch_bounds__(256) void k1_hsd_stats(const float* __restrict__ hsd,
                                                    double* __restrict__ stats, int N) {
    double s = 0.0, s2 = 0.0;
    for (int i = blockIdx.x * 256 + threadIdx.x; i < N; i += gridDim.x * 256) {
        double v = (double)hsd[i];
        s += v; s2 += v * v;
    }
    for (int off = 32; off > 0; off >>= 1) {
        s  += __shfl_down(s,  off, 64);
        s2 += __shfl_down(s2, off, 64);
    }
    __shared__ double ls[4], ls2[4];
    int wid = threadIdx.x >> 6, lid = threadIdx.x & 63;
    if (lid == 0) { ls[wid] = s; ls2[wid] = s2; }
    __syncthreads();
    if (threadIdx.x == 0) {
        double ts = 0.0, t2 = 0.0;
        for (int w = 0; w < 4; ++w) { ts += ls[w]; t2 += ls2[w]; }
        atomicAdd(stats, ts);
        atomicAdd(stats + 1, t2);
    }
}

// ---------- K2: hsd_norm + gate alpha_bar ----------
__global__ __launch_bounds__(256) void k2_node_prep(const float* __restrict__ hsd,
                                                    const double* __restrict__ stats,
                                                    const float* __restrict__ Wn1,
                                                    const float* __restrict__ bn1,
                                                    const float* __restrict__ Wn2,
                                                    const float* __restrict__ bn2,
                                                    float* __restrict__ hsd_norm,
                                                    float* __restrict__ alpha_bar, int N) {
    int n = blockIdx.x * 256 + threadIdx.x;
    if (n >= N) return;
    double sum = stats[0], sumsq = stats[1];
    double mean = sum / (double)N;
    double var  = (sumsq - sum * sum / (double)N) / (double)(N - 1);
    float stdv  = (float)sqrt(var);
    float hn = (hsd[n] - (float)mean) / (stdv + 1e-8f);
    hsd_norm[n] = hn;
    float acc = bn2[0];
#pragma unroll
    for (int k = 0; k < NHID; ++k)
        acc += fmaxf(fmaf(hn, Wn1[k], bn1[k]), 0.0f) * Wn2[k];
    alpha_bar[n] = 1.0f / (1.0f + __expf(-acc));
}

// ---------- S1: per-tile fine-bin histograms ----------
__global__ __launch_bounds__(256) void s1_hist(const int* __restrict__ ei,
                                               int* __restrict__ hist,
                                               int E, int NB, int T, int M) {
    __shared__ int hv[1024], hu[1024];
    int t = threadIdx.x;
    for (int b = t; b < 1024; b += 256) { hv[b] = 0; hu[b] = 0; }
    __syncthreads();
    int base = blockIdx.x * TILE;
    for (int i = t; i < TILE; i += 256) {
        int e = base + i;
        if (e < E) {
            int u = ei[e], v = ei[E + e];
            atomicAdd(&hv[v >> BSH], 1);
            atomicAdd(&hu[u >> BSH], 1);
        }
    }
    __syncthreads();
    for (int b = t; b < NB; b += 256) {
        hist[b * T + blockIdx.x] = hv[b];
        hist[M + b * T + blockIdx.x] = hu[b];
    }
}

// ---------- Scan ----------
__global__ __launch_bounds__(256) void scan_k1(const int* __restrict__ cnt,
                                               int* __restrict__ out,
                                               int* __restrict__ partials, int N) {
    __shared__ int lds[256];
    int base = blockIdx.x * SCAN_CHUNK;
    int t = threadIdx.x;
    int v[4]; int loc = 0;
#pragma unroll
    for (int k = 0; k < 4; ++k) {
        int idx = base + t * 4 + k;
        v[k] = (idx < N) ? cnt[idx] : 0;
        loc += v[k];
    }
    lds[t] = loc; __syncthreads();
    for (int off = 1; off < 256; off <<= 1) {
        int a = (t >= off) ? lds[t - off] : 0;
        __syncthreads();
        lds[t] += a;
        __syncthreads();
    }
    int run = (t > 0) ? lds[t - 1] : 0;
    if (t == 255) partials[blockIdx.x] = lds[255];
#pragma unroll
    for (int k = 0; k < 4; ++k) {
        run += v[k];
        int idx = base + t * 4 + k;
        if (idx < N) out[idx + 1] = run;
    }
    if (blockIdx.x == 0 && t == 0) out[0] = 0;
}

__global__ __launch_bounds__(256) void scan_k2(int* __restrict__ partials, int B) {
    __shared__ int lds[256];
    int t = threadIdx.x;
    int v[4]; int loc = 0;
#pragma unroll
    for (int k = 0; k < 4; ++k) {
        int idx = t * 4 + k;
        v[k] = (idx < B) ? partials[idx] : 0;
        loc += v[k];
    }
    lds[t] = loc; __syncthreads();
    for (int off = 1; off < 256; off <<= 1) {
        int a = (t >= off) ? lds[t - off] : 0;
        __syncthreads();
        lds[t] += a;
        __syncthreads();
    }
    int run = (t > 0) ? lds[t - 1] : 0;
#pragma unroll
    for (int k = 0; k < 4; ++k) {
        int idx = t * 4 + k;
        if (idx < B) { partials[idx] = run; run += v[k]; }
    }
}

__global__ __launch_bounds__(256) void scan_k3(int* __restrict__ out,
                                               const int* __restrict__ partials, int N) {
    int i = blockIdx.x * 256 + threadIdx.x;
    if (i >= N) return;
    out[i + 1] += partials[i / SCAN_CHUNK];
}

// ---------- S2: scatter edges into fine v-bin order; u into fine u-bin order ----------
__global__ __launch_bounds__(256) void s2_scatter(const int* __restrict__ ei,
                                                  const int* __restrict__ scanAll,
                                                  int2* __restrict__ coarse,
                                                  int* __restrict__ coarseU,
                                                  int E, int NB, int T, int M) {
    __shared__ int curV[1024], curU[1024];
    int t = threadIdx.x;
    for (int b = t; b < NB; b += 256) {
        curV[b] = scanAll[b * T + blockIdx.x];
        curU[b] = scanAll[M + b * T + blockIdx.x] - E;
    }
    __syncthreads();
    int base = blockIdx.x * TILE;
    for (int i = t; i < TILE; i += 256) {
        int e = base + i;
        if (e < E) {
            int u = ei[e], v = ei[E + e];
            int pv = atomicAdd(&curV[v >> BSH], 1);
            coarse[pv] = make_int2(u, v);
            int pu = atomicAdd(&curU[u >> BSH], 1);
            coarseU[pu] = u;
        }
    }
}

// ---------- S3b: per u-bin exact count -> inv_ssrc ----------
__global__ __launch_bounds__(256) void s3b_srccnt(const int* __restrict__ coarseU,
                                                  const int* __restrict__ scanAll,
                                                  float* __restrict__ inv_ssrc,
                                                  int N, int E, int NB, int T, int M) {
    __shared__ int cnt[NBIN];
    int t = threadIdx.x;
    int bin = blockIdx.x;
    int start = scanAll[M + bin * T] - E;
    int endv  = scanAll[M + (bin + 1) * T] - E;
    if (t < NBIN) cnt[t] = 0;
    __syncthreads();
    for (int i = start + t; i < endv; i += 256) atomicAdd(&cnt[coarseU[i] & BMASK], 1);
    __syncthreads();
    int vglob = (bin << BSH) + t;
    if (t < NBIN && vglob < N) inv_ssrc[vglob] = rsqrtf(fmaxf((float)cnt[t], 1.0f));
}

// ---------- K3e: edge MLP via swapped-operand MFMA ----------
// H^T[hid][edge] = We1^T (A, VGPR-resident) @ edge_in^T (B, LDS tile).
// hsd features folded into C-init; We2 dot in-register; 2 shfl per 16 edges.
__global__ __launch_bounds__(256) void k3e_mlp(const unsigned* __restrict__ xbf,
                                               const float* __restrict__ hsd_norm,
                                               const float* __restrict__ We1,
                                               const float* __restrict__ be1,
                                               const float* __restrict__ We2,
                                               const float* __restrict__ be2,
                                               const int2* __restrict__ esorted,
                                               float* __restrict__ logit, int E) {
    __shared__ uint4 sdiff4[16 * TILE_B / 16];   // 17408 B, 16 tiles of [4 chunk][16 edge]
    __shared__ unsigned sh[EPB];                 // packed hsdu|hsdv per edge
    char* sdiff = (char*)sdiff4;

    int t = threadIdx.x;
    int base = blockIdx.x * EPB;
    int l = t & 63, w = t >> 6;
    int hq = l >> 4, hr = l & 15;

    // ---- staging: 4 lanes per edge, 16B (8 features) each, conflict-free tiles ----
    int q = t & 3;
#pragma unroll
    for (int p = 0; p < 4; ++p) {
        int s = (t >> 2) + 64 * p;
        int e = base + s;
        int2 uv = esorted[(e < E) ? e : (E - 1)];
        uint4 au = *(const uint4*)(xbf + (size_t)uv.x * 16 + q * 4);
        uint4 av = *(const uint4*)(xbf + (size_t)uv.y * 16 + q * 4);
        uint4 outv;
        outv.x = pkdiff(au.x, av.x);
        outv.y = pkdiff(au.y, av.y);
        outv.z = pkdiff(au.z, av.z);
        outv.w = pkdiff(au.w, av.w);
        *(uint4*)(sdiff + (s >> 4) * TILE_B + q * TPAD + (s & 15) * 16) = outv;
        if (q == 0)
            sh[s] = (unsigned)f2bf(hsd_norm[uv.x]) |
                    ((unsigned)f2bf(hsd_norm[uv.y]) << 16);
    }

    // ---- A-frags (weights) + epilogue constants, lane-resident ----
    unsigned short aw0[8], aw1[8];
#pragma unroll
    for (int b = 0; b < 8; ++b) {
        aw0[b] = f2bf(We1[(hq * 8 + b + 2) * EHID + hr]);
        aw1[b] = f2bf(We1[(hq * 8 + b + 2) * EHID + 16 + hr]);
    }
    short8v A0 = *(const short8v*)aw0;
    short8v A1 = *(const short8v*)aw1;
    float W0a[4], W1a[4], bea[4], W2a[4], W0b[4], W1b[4], beb[4], W2b[4];
#pragma unroll
    for (int r = 0; r < 4; ++r) {
        int h = hq * 4 + r;
        W0a[r] = We1[h];        W1a[r] = We1[EHID + h];
        bea[r] = be1[h];        W2a[r] = We2[h];
        int h2 = h + 16;
        W0b[r] = We1[h2];       W1b[r] = We1[EHID + h2];
        beb[r] = be1[h2];       W2b[r] = We2[h2];
    }
    float b2 = be2[0];
    __syncthreads();

    // ---- per 16-edge group: 1 b128 + 1 b32 read, 2 MFMA, in-reg epilogue ----
#pragma unroll
    for (int gi = 0; gi < 4; ++gi) {
        int g = w * 4 + gi;
        short8v Bf = *(const short8v*)(sdiff + g * TILE_B + hq * TPAD + hr * 16);
        unsigned hp = sh[g * 16 + hr];
        float hu = bflo(hp), hv = bfhi(hp);
        f32x4 c0, c1;
#pragma unroll
        for (int r = 0; r < 4; ++r) {
            c0[r] = fmaf(hv, W1a[r], fmaf(hu, W0a[r], bea[r]));
            c1[r] = fmaf(hv, W1b[r], fmaf(hu, W0b[r], beb[r]));
        }
        c0 = __builtin_amdgcn_mfma_f32_16x16x32_bf16(A0, Bf, c0, 0, 0, 0);
        c1 = __builtin_amdgcn_mfma_f32_16x16x32_bf16(A1, Bf, c1, 0, 0, 0);
        float vs = 0.0f;
#pragma unroll
        for (int r = 0; r < 4; ++r) {
            vs = fmaf(fmaxf(c0[r], 0.0f), W2a[r], vs);
            vs = fmaf(fmaxf(c1[r], 0.0f), W2b[r], vs);
        }
        vs += __shfl_xor(vs, 16, 64);
        vs += __shfl_xor(vs, 32, 64);
        int eo = base + g * 16 + hr;
        if (hq == 0 && eo < E) logit[eo] = (vs + b2) * INV_TAU;
    }
}

// ---------- K6a: per-bin tables + sorted scatter of per-edge coefficients ----------
__global__ __launch_bounds__(512) void k6a_tab(const int2* __restrict__ coarse,
                                               const float* __restrict__ logit,
                                               const int* __restrict__ scanAll,
                                               const float* __restrict__ inv_ssrc,
                                               const float* __restrict__ alpha_bar,
                                               int* __restrict__ usrc,
                                               float* __restrict__ coefG,
                                               int* __restrict__ dst_off,
                                               float* __restrict__ selfc,
                                               int N, int E, int NB, int T) {
    __shared__ int      su[CAP];
    __shared__ float    slg[CAP];
    __shared__ int      cnt[NBIN];
    __shared__ unsigned mEnc[NBIN];
    __shared__ float    den[NBIN], cA[NBIN], cB[NBIN];
    __shared__ int      base_[NBIN], cur_[NBIN];

    int t = threadIdx.x;
    int bin = blockIdx.x;
    int start = scanAll[bin * T];
    int n = scanAll[(bin + 1) * T] - start;
    if (n > CAP) n = CAP;

    if (t < NBIN) { cnt[t] = 0; mEnc[t] = 0u; den[t] = 0.0f; }
    __syncthreads();

    for (int i = t; i < n; i += 512) {
        int2 c = coarse[start + i];
        float lgv = logit[start + i];
        int vl = c.y & BMASK;
        su[i] = c.x | (vl << 17);
        slg[i] = lgv;
        atomicAdd(&cnt[vl], 1);
        atomicMax(&mEnc[vl], enc_f32(lgv));
    }
    __syncthreads();

    for (int i = t; i < n; i += 512) {
        int vl = su[i] >> 17;
        atomicAdd(&den[vl], __expf(slg[i] - dec_f32(mEnc[vl])));
    }
    __syncthreads();

    for (int off = 1; off < NBIN; off <<= 1) {
        int a = 0;
        if (t < NBIN && t >= off) a = cnt[t - off];
        __syncthreads();
        if (t < NBIN) cnt[t] += a;
        __syncthreads();
    }
    if (t < NBIN) {
        int b0 = (t > 0) ? cnt[t - 1] : 0;
        base_[t] = b0; cur_[t] = b0;
        int vg = (bin << BSH) + t;
        if (vg < N) {
            float ab = alpha_bar[vg];
            float d = den[t];
            float inv_den = 1.0f / (d + 1e-16f);
            int deg = cnt[t] - b0;
            cA[t] = -ab * inv_den;
            cB[t] = (1.0f - ab) * rsqrtf(fmaxf((float)deg, 1.0f));
            dst_off[vg] = start + b0;
            selfc[vg] = ab * (d * inv_den);
        }
    }
    if (bin == 0 && t == 0) dst_off[N] = E;
    __syncthreads();

    for (int i = t; i < n; i += 512) {
        int up = su[i];
        int vl = up >> 17;
        int u = up & 0x1FFFF;
        int p = start + atomicAdd(&cur_[vl], 1);
        float coef = fmaf(cA[vl], __expf(slg[i] - dec_f32(mEnc[vl])), cB[vl] * inv_ssrc[u]);
        usrc[p] = u;
        coefG[p] = coef;
    }
}

// ---------- K7: pure gather on bf16 x: 16 lanes per node, 8-deep unroll ----------
__global__ __launch_bounds__(256) void k7_gather(const unsigned* __restrict__ xbf,
                                                 const int* __restrict__ dst_off,
                                                 const int* __restrict__ usrc,
                                                 const float* __restrict__ coefG,
                                                 const float* __restrict__ selfc,
                                                 float* __restrict__ out, int N) {
    int v = blockIdx.x * 16 + (threadIdx.x >> 4);
    if (v >= N) return;
    int l = threadIdx.x & 15;

    int beg = dst_off[v], end = dst_off[v + 1];

    float a0 = 0.0f, a1 = 0.0f;
    int j = beg;
    for (; j + 7 < end; j += 8) {
        int u_[8]; float c_[8]; unsigned q_[8];
#pragma unroll
        for (int k = 0; k < 8; ++k) { u_[k] = usrc[j + k]; c_[k] = coefG[j + k]; }
#pragma unroll
        for (int k = 0; k < 8; ++k) q_[k] = xbf[(size_t)u_[k] * 16 + l];
#pragma unroll
        for (int k = 0; k < 8; ++k) {
            a0 = fmaf(c_[k], bflo(q_[k]), a0);
            a1 = fmaf(c_[k], bfhi(q_[k]), a1);
        }
    }
    for (; j < end; ++j) {
        unsigned q0 = xbf[(size_t)usrc[j] * 16 + l];
        float c0 = coefG[j];
        a0 = fmaf(c0, bflo(q0), a0); a1 = fmaf(c0, bfhi(q0), a1);
    }
    float sc = selfc[v];
    unsigned qv = xbf[(size_t)v * 16 + l];
    a0 = fmaf(sc, bflo(qv), a0);
    a1 = fmaf(sc, bfhi(qv), a1);
    float2 r; r.x = a0; r.y = a1;
    *(float2*)(out + (size_t)v * D_FEAT + 2 * l) = r;
}

extern "C" void kernel_launch(void* const* d_in, const int* in_sizes, int n_in,
                              void* d_out, int out_size, void* d_ws, size_t ws_size,
                              hipStream_t stream) {
    const float* x    = (const float*)d_in[0];
    const float* hsd  = (const float*)d_in[1];
    const float* We1  = (const float*)d_in[2];
    const float* be1  = (const float*)d_in[3];
    const float* We2  = (const float*)d_in[4];
    const float* be2  = (const float*)d_in[5];
    const float* Wn1  = (const float*)d_in[6];
    const float* bn1  = (const float*)d_in[7];
    const float* Wn2  = (const float*)d_in[8];
    const float* bn2  = (const float*)d_in[9];
    const int*   ei   = (const int*)d_in[10];
    float* out = (float*)d_out;

    const int N = in_sizes[1];
    const int E = in_sizes[10] / 2;
    const int NB = (N + NBIN - 1) >> BSH;
    const int T  = (E + TILE - 1) / TILE;
    const int M  = NB * T;
    const int M2 = 2 * M;

    char* ws = (char*)d_ws;
    size_t o = 0;
    auto alloc = [&](size_t bytes) { size_t r = o; o += (bytes + 255) & ~(size_t)255; return r; };
    double* stats     = (double*)(ws + alloc(16));
    float*  inv_ssrc  = (float*)(ws + alloc((size_t)4 * N));
    float*  hsd_norm  = (float*)(ws + alloc((size_t)4 * N));
    float*  alpha_bar = (float*)(ws + alloc((size_t)4 * N));
    float*  selfc     = (float*)(ws + alloc((size_t)4 * N));
    int*    dst_off   = (int*)(ws + alloc((size_t)4 * (N + 1)));
    int*    partials  = (int*)(ws + alloc(4096));
    int*    bufH      = (int*)(ws + alloc((size_t)4 * M2));
    int*    bufS      = (int*)(ws + alloc((size_t)4 * (M2 + 1)));
    int2*   coarse    = (int2*)(ws + alloc((size_t)8 * E));
    int*    coarseU   = (int*)(ws + alloc((size_t)4 * E));   // dead after s3b -> xbf
    float*  logit     = (float*)(ws + alloc((size_t)4 * E));
    int*    usrc      = (int*)(ws + alloc((size_t)4 * E));
    float*  coefG     = (float*)(ws + alloc((size_t)4 * E));
    unsigned* xbf     = (unsigned*)coarseU;   // bf16 x rows, written after s3b

    hipMemsetAsync(d_ws, 0, 256, stream);

    k1_hsd_stats<<<256, 256, 0, stream>>>(hsd, stats, N);
    k2_node_prep<<<(N + 255) / 256, 256, 0, stream>>>(hsd, stats, Wn1, bn1, Wn2, bn2,
                                                      hsd_norm, alpha_bar, N);

    s1_hist<<<T, 256, 0, stream>>>(ei, bufH, E, NB, T, M);

    int Bs = (M2 + SCAN_CHUNK - 1) / SCAN_CHUNK;
    scan_k1<<<Bs, 256, 0, stream>>>(bufH, bufS, partials, M2);
    scan_k2<<<1, 256, 0, stream>>>(partials, Bs);
    scan_k3<<<(M2 + 255) / 256, 256, 0, stream>>>(bufS, partials, M2);

    s2_scatter<<<T, 256, 0, stream>>>(ei, bufS, coarse, coarseU, E, NB, T, M);
    s3b_srccnt<<<NB, 256, 0, stream>>>(coarseU, bufS, inv_ssrc, N, E, NB, T, M);
    kx_pack<<<(N * (D_FEAT / 2) + 255) / 256, 256, 0, stream>>>(x, xbf, N * (D_FEAT / 2));
    k3e_mlp<<<(E + EPB - 1) / EPB, 256, 0, stream>>>(xbf, hsd_norm, We1, be1, We2, be2,
                                                     coarse, logit, E);
    k6a_tab<<<NB, 512, 0, stream>>>(coarse, logit, bufS, inv_ssrc, alpha_bar,
                                    usrc, coefG, dst_off, selfc, N, E, NB, T);
    k7_gather<<<(N + 15) / 16, 256, 0, stream>>>(xbf, dst_off, usrc, coefG, selfc, out, N);
}